// Round 16
// baseline (1486.919 us; speedup 1.0000x reference)
//
#include <hip/hip_runtime.h>
#include <stdint.h>

#define NB 512   // batch
#define NT 32    // time steps
#define NIN 8    // input feats
#define NIN1 9   // + y_prev
#define NH 64    // hidden
#define NP 256   // particles
#define NTHR 512 // 8 waves: wave wq owns gate-rows r' in [32wq, 32wq+32)
#define HROW 68  // f16 row stride: 136 B = 34 dwords -> 2-way bank alias (free)

typedef __attribute__((ext_vector_type(8))) _Float16 f16x8;
typedef __attribute__((ext_vector_type(16))) float f32x16;

struct FKeys { uint32_t a[NT]; uint32_t b[NT]; };

// ---------------- Threefry-2x32-20 (exact JAX semantics) ----------------
__host__ __device__ __forceinline__ void tfr(uint32_t& x0, uint32_t& x1, int r) {
  x0 += x1; x1 = (x1 << r) | (x1 >> (32 - r)); x1 ^= x0;
}

__host__ __device__ __forceinline__ void threefry2x32(uint32_t k0, uint32_t k1,
                                                      uint32_t& x0, uint32_t& x1) {
  uint32_t k2 = k0 ^ k1 ^ 0x1BD11BDAu;
  x0 += k0; x1 += k1;
  tfr(x0,x1,13); tfr(x0,x1,15); tfr(x0,x1,26); tfr(x0,x1,6);
  x0 += k1; x1 += k2 + 1u;
  tfr(x0,x1,17); tfr(x0,x1,29); tfr(x0,x1,16); tfr(x0,x1,24);
  x0 += k2; x1 += k0 + 2u;
  tfr(x0,x1,13); tfr(x0,x1,15); tfr(x0,x1,26); tfr(x0,x1,6);
  x0 += k0; x1 += k1 + 3u;
  tfr(x0,x1,17); tfr(x0,x1,29); tfr(x0,x1,16); tfr(x0,x1,24);
  x0 += k1; x1 += k2 + 4u;
  tfr(x0,x1,13); tfr(x0,x1,15); tfr(x0,x1,26); tfr(x0,x1,6);
  x0 += k2; x1 += k0 + 5u;
}

// bits -> uniform -> sqrt(2)*erfinv  (XLA f32 path; __logf variant validated
// R11 at absmax 0.5).
__device__ __forceinline__ float normal_from_bits(uint32_t bits) {
  float f = __uint_as_float((bits >> 9) | 0x3f800000u) - 1.0f;
  const float lo = -0.99999994f;
  float u = fmaxf(lo, fmaf(f, 2.0f, lo));
  float w = -__logf(fmaf(-u, u, 1.0f));
  float p;
  if (w < 5.0f) {
    w -= 2.5f;
    p = 2.81022636e-08f;
    p = fmaf(p, w, 3.43273939e-07f);
    p = fmaf(p, w, -3.5233877e-06f);
    p = fmaf(p, w, -4.39150654e-06f);
    p = fmaf(p, w, 0.00021858087f);
    p = fmaf(p, w, -0.00125372503f);
    p = fmaf(p, w, -0.00417768164f);
    p = fmaf(p, w, 0.246640727f);
    p = fmaf(p, w, 1.50140941f);
  } else {
    w = sqrtf(w) - 3.0f;
    p = -0.000200214257f;
    p = fmaf(p, w, 0.000100950558f);
    p = fmaf(p, w, 0.00134934322f);
    p = fmaf(p, w, -0.00367342844f);
    p = fmaf(p, w, 0.00573950773f);
    p = fmaf(p, w, -0.0076224613f);
    p = fmaf(p, w, 0.00943887047f);
    p = fmaf(p, w, 1.00167406f);
    p = fmaf(p, w, 2.83297682f);
  }
  return 1.41421356f * (p * u);
}

__device__ __forceinline__ float frcp(float x) { return __builtin_amdgcn_rcpf(x); }
__device__ __forceinline__ float fsigmoid(float x) { return frcp(1.0f + __expf(-x)); }
__device__ __forceinline__ float ftanh(float x) { return 1.0f - 2.0f * frcp(1.0f + __expf(2.0f * x)); }

// f32 -> f16 bits (RNE)
__device__ __forceinline__ uint32_t pack_f16(float x) {
  union { _Float16 h; uint16_t u; } c;
  c.h = (_Float16)x;
  return (uint32_t)c.u;
}

// 8B-aligned LDS f16x8 load (two ds_read_b64, 2-way alias at HROW=68)
__device__ __forceinline__ f16x8 ld8h(const _Float16* p) {
  union { f16x8 v; uint64_t q[2]; } u;
  u.q[0] = *(const uint64_t*)(p);
  u.q[1] = *(const uint64_t*)(p + 4);
  return u.v;
}

// ---------------- main kernel: one block (512 thr) per batch elem ----------------
// R15 structure (single-f16 h, h0 unsorted staging + phase-F permute copy), with
// wf_r/wp_r/std_r register arrays evicted to volatile LDS broadcast reads.
// Target: arch VGPR <= 112 so VGPR+accAGPR <= 128 -> 2 blocks/CU (4 waves/SIMD).
__global__ __launch_bounds__(NTHR, 2)
void pf_main(const float* __restrict__ input_data, const float* __restrict__ y_prev,
             const float* __restrict__ Wv, const float* __restrict__ bv,
             const float* __restrict__ W_ih, const float* __restrict__ W_hh,
             const float* __restrict__ b_ih, const float* __restrict__ b_hh,
             const float* __restrict__ Wp, const float* __restrict__ bp,
             const float* __restrict__ Wf, const float* __restrict__ bf,
             float* __restrict__ out, float* __restrict__ gw,
             FKeys fk)
{
  __shared__ __align__(16) _Float16 h1_s[NP * HROW];  // 34.8 KB sorted h
  __shared__ __align__(16) _Float16 h0_s[NP * HROW];  // 34.8 KB unsorted new h
  __shared__ __align__(16) float xg_s[NP];
  __shared__ __align__(16) float proj_s[NP];
  __shared__ float lp_s[NP];
  __shared__ float wsum_s[NP];
  __shared__ int   rankP_s[2 * NP];
  __shared__ float hsum_s[NH];
  __shared__ float std_s[NH];
  __shared__ float Wf_s[NH];
  __shared__ float Wp_s[NH];
  __shared__ float xs_s[16];

  const int tid  = threadIdx.x;
  const int b    = blockIdx.x;
  const int lane = tid & 63;
  const int wq   = tid >> 6;          // wave 0..7: gate-row group
  const int ln31 = lane & 31;
  const int h5   = lane >> 5;

  for (int i = tid; i < NP * HROW; i += NTHR) h1_s[i] = (_Float16)0.0f;
  if (tid < NP) wsum_s[tid] = 0.0f;
  if (tid < NH) {
    hsum_s[tid] = 0.0f;
    Wf_s[tid] = Wf[tid];
    Wp_s[tid] = Wp[tid];
  }

  const float bf0 = bf[0];
  const float bp0 = bp[0];
  const uint32_t bsh = (uint32_t)b << 6;

  // W' A-fragments (single f16), loaded ONCE: r' = 32wq+ln31, orig row (r'&3)*64+(r'>>2)
  const int rp   = 32 * wq + ln31;
  const int orig = (rp & 3) * NH + (rp >> 2);
  f16x8 w1f[4];
  #pragma unroll
  for (int kt = 0; kt < 4; ++kt) {
    #pragma unroll
    for (int e = 0; e < 8; ++e)
      w1f[kt][e] = (_Float16)W_hh[orig * NH + kt * 16 + h5 * 8 + e];
  }

  // c state in registers: static cell ownership, never sorted
  float cA[4][4], cB[4][4];
  #pragma unroll
  for (int mi = 0; mi < 4; ++mi) {
    #pragma unroll
    for (int q = 0; q < 4; ++q) { cA[mi][q] = 0.0f; cB[mi][q] = 0.0f; }
  }

  auto finalize_init = [&]() {
    if (tid < NH) {
      float v = bv[tid];
      const float* wvr = Wv + tid * (NIN1 + NH);
      #pragma unroll
      for (int i = 0; i < NIN1; ++i) v = fmaf(xs_s[i], wvr[i], v);
      #pragma unroll
      for (int k = 0; k < NH; ++k)
        v = fmaf(hsum_s[k] * (1.0f / NP), wvr[NIN1 + k], v);
      std_s[tid] = fmaxf(v, 0.0f) + log1pf(expf(-fabsf(v)));   // softplus, libm exact
    }
    if (tid < NP) {
      const int orow = (tid & 3) * NH + (tid >> 2);
      float a = b_ih[orow] + b_hh[orow];
      const float* wr = W_ih + orow * NIN1;
      #pragma unroll
      for (int i = 0; i < NIN1; ++i) a = fmaf(xs_s[i], wr[i], a);
      xg_s[tid] = a;
      proj_s[tid] = bf0;
      float xp = bp0;
      #pragma unroll
      for (int i = 0; i < NIN1; ++i) xp = fmaf(xs_s[i], Wp[NH + i], xp);
      lp_s[tid] = xp;
    }
  };

  if (tid < NIN) xs_s[tid] = input_data[(b * NT + 0) * NIN + tid];
  if (tid == NIN) xs_s[NIN] = y_prev[b * NT + 0];
  __syncthreads();
  finalize_init();
  __syncthreads();

  for (int t = 0; t < NT; ++t) {
    // ================= phase A: MFMA + elementwise (+ xs_{t+1} prefetch) ========
    if (tid < 16 && t + 1 < NT) {
      if (tid < NIN) xs_s[tid] = input_data[(b * NT + t + 1) * NIN + tid];
      if (tid == NIN) xs_s[NIN] = y_prev[b * NT + t + 1];
    }

    const uint32_t fk0 = fk.a[t], fk1 = fk.b[t];
    float hs[4] = {0.0f, 0.0f, 0.0f, 0.0f};

    #pragma unroll
    for (int mi = 0; mi < 4; ++mi) {
      const int pA = mi * 32 + ln31;

      // ---- tile A (rows pA) ----
      f32x16 acc;
      #pragma unroll
      for (int q = 0; q < 4; ++q) {
        const float4 v = *(const float4*)&xg_s[32 * wq + 8 * q + 4 * h5];
        acc[4 * q + 0] = v.x; acc[4 * q + 1] = v.y;
        acc[4 * q + 2] = v.z; acc[4 * q + 3] = v.w;
      }
      #pragma unroll
      for (int kt = 0; kt < 4; ++kt) {
        const f16x8 b1 = ld8h(&h1_s[pA * HROW + kt * 16 + h5 * 8]);
        acc = __builtin_amdgcn_mfma_f32_32x32x16_f16(w1f[kt], b1, acc, 0, 0, 0);
      }
      float hlA[4];
      #pragma unroll
      for (int q = 0; q < 4; ++q) {
        float si = fsigmoid(acc[4 * q + 0]);
        float sf = fsigmoid(acc[4 * q + 1]);
        float so = fsigmoid(acc[4 * q + 3]);
        float cn = sf * cA[mi][q] + si * ftanh(acc[4 * q + 2]);
        cA[mi][q] = cn;
        hlA[q] = so * ftanh(cn);
      }
      // ---- tile B (rows pA+128) ----
      #pragma unroll
      for (int q = 0; q < 4; ++q) {
        const float4 v = *(const float4*)&xg_s[32 * wq + 8 * q + 4 * h5];
        acc[4 * q + 0] = v.x; acc[4 * q + 1] = v.y;
        acc[4 * q + 2] = v.z; acc[4 * q + 3] = v.w;
      }
      #pragma unroll
      for (int kt = 0; kt < 4; ++kt) {
        const f16x8 b1 = ld8h(&h1_s[(pA + 128) * HROW + kt * 16 + h5 * 8]);
        acc = __builtin_amdgcn_mfma_f32_32x32x16_f16(w1f[kt], b1, acc, 0, 0, 0);
      }
      float plA = 0.0f, lpA = 0.0f, plB = 0.0f, lpB = 0.0f;
      uint32_t sh[4];
      #pragma unroll
      for (int q = 0; q < 4; ++q) {
        const int kq = 8 * wq + 2 * q + h5;
        // volatile LDS broadcasts: keep these OUT of long-lived registers
        const float stdv = *(volatile const float*)&std_s[kq];
        const float wfv  = *(volatile const float*)&Wf_s[kq];
        const float wpv  = *(volatile const float*)&Wp_s[kq];
        float si = fsigmoid(acc[4 * q + 0]);
        float sf = fsigmoid(acc[4 * q + 1]);
        float so = fsigmoid(acc[4 * q + 3]);
        float cnB = sf * cB[mi][q] + si * ftanh(acc[4 * q + 2]);
        cB[mi][q] = cnB;
        float hlB = so * ftanh(cnB);
        uint32_t x0 = ((uint32_t)pA << 15) | bsh | (uint32_t)kq;
        uint32_t x1 = x0 + (1u << 22);
        threefry2x32(fk0, fk1, x0, x1);
        float hA = fmaf(normal_from_bits(x0), stdv, hlA[q]);
        float hB = fmaf(normal_from_bits(x1), stdv, hlB);
        hs[q] += hA + hB;
        plA = fmaf(hA, wfv, plA); lpA = fmaf(hA, wpv, lpA);
        plB = fmaf(hB, wfv, plB); lpB = fmaf(hB, wpv, lpB);
        // cross-lane exchange: assemble this thread's write row-half (f16 pair)
        const uint32_t pkA = pack_f16(hA);
        const uint32_t pkB = pack_f16(hB);
        const uint32_t send = h5 ? pkA : pkB;
        const uint32_t got  = (uint32_t)__shfl_xor((int)send, 32, 64);
        const uint32_t ev = h5 ? got : pkA;   // k = 8wq+2q   (even)
        const uint32_t od = h5 ? pkB : got;   // k = 8wq+2q+1 (odd)
        sh[q] = (ev & 0xffffu) | (od << 16);
      }
      // immediate unsorted store -> h0_s (frees the staging registers)
      {
        const int row = pA + (h5 ? 128 : 0);
        _Float16* d = &h0_s[row * HROW + 8 * wq];
        *(uint64_t*)(d)     = (uint64_t)sh[0] | ((uint64_t)sh[1] << 32);
        *(uint64_t*)(d + 4) = (uint64_t)sh[2] | ((uint64_t)sh[3] << 32);
      }
      plA += __shfl_xor(plA, 32, 64); lpA += __shfl_xor(lpA, 32, 64);
      plB += __shfl_xor(plB, 32, 64); lpB += __shfl_xor(lpB, 32, 64);
      if (lane < 32) {
        atomicAdd(&proj_s[pA], plA);
        atomicAdd(&lp_s[pA], lpA);
        atomicAdd(&proj_s[pA + 128], plB);
        atomicAdd(&lp_s[pA + 128], lpB);
      }
    }
    // hsum: butterfly over 32-lane group; k = 8wq+2q+h5
    #pragma unroll
    for (int q = 0; q < 4; ++q) {
      float s = hs[q];
      s += __shfl_xor(s, 1, 64); s += __shfl_xor(s, 2, 64); s += __shfl_xor(s, 4, 64);
      s += __shfl_xor(s, 8, 64); s += __shfl_xor(s, 16, 64);
      if (ln31 == q) hsum_s[8 * wq + 2 * q + h5] = s;
    }
    __syncthreads();   // b1: h1 reads + h0 writes + proj/lp atomics + xs_next done

    // ================= phase R: split stable-rank (512 half-jobs) =================
    {
      const int ph = tid & (NP - 1);
      const int hh = tid >> 8;
      const float pv = proj_s[ph];
      int rk = 0;
      const float4* c4 = (const float4*)proj_s;
      #pragma unroll 8
      for (int q4 = 32 * hh; q4 < 32 * hh + 32; ++q4) {
        float4 v = c4[q4];
        int qb = q4 * 4;
        rk += (v.x < pv || (v.x == pv && qb + 0 < ph)) ? 1 : 0;
        rk += (v.y < pv || (v.y == pv && qb + 1 < ph)) ? 1 : 0;
        rk += (v.z < pv || (v.z == pv && qb + 2 < ph)) ? 1 : 0;
        rk += (v.w < pv || (v.w == pv && qb + 3 < ph)) ? 1 : 0;
      }
      rankP_s[hh * NP + ph] = rk;
    }
    __syncthreads();   // b2: rank partials ready

    // ================= phase F: copy h0[p] -> h1[rank[p]] + wsum + next init ====
    {
      const int ph = tid & (NP - 1);
      const int hh = tid >> 8;
      const int rank = rankP_s[ph] + rankP_s[NP + ph];
      const uint64_t* s = (const uint64_t*)&h0_s[ph * HROW + 32 * hh];
      const uint64_t v0 = s[0], v1 = s[1], v2 = s[2], v3 = s[3];
      uint64_t* d = (uint64_t*)&h1_s[rank * HROW + 32 * hh];
      d[0] = v0; d[1] = v1; d[2] = v2; d[3] = v3;
      if (hh == 0) wsum_s[rank] += __expf(lp_s[ph]);   // permutation -> race-free
    }
    finalize_init();
    __syncthreads();   // b3 (loop end): h writes + next-step init visible
  }

  // ---- epilogue: y_pred[b] = mean_p(h_fin) @ Wf + bf ----
  if (tid < NH) {
    float hm = hsum_s[tid] * (1.0f / NP);
    float contrib = hm * Wf_s[tid];
    contrib += __shfl_xor(contrib, 32, 64);
    contrib += __shfl_xor(contrib, 16, 64);
    contrib += __shfl_xor(contrib, 8, 64);
    contrib += __shfl_xor(contrib, 4, 64);
    contrib += __shfl_xor(contrib, 2, 64);
    contrib += __shfl_xor(contrib, 1, 64);
    if (tid == 0) out[b] = contrib + bf0;
  }
  if (tid < NP) gw[(size_t)tid * NB + b] = wsum_s[tid];
}

// weights[i] = (1/256) * sum_{j<256} gw[(i>>1)*512 + (i&1)*256 + j]
__global__ __launch_bounds__(64, 1)
void pf_weights(const float* __restrict__ gw, float* __restrict__ out) {
  int i = blockIdx.x;
  int lane = threadIdx.x;
  const float* src = gw + ((size_t)(i >> 1)) * NB + (size_t)(i & 1) * NP;
  float4 v = ((const float4*)src)[lane];
  float s = (v.x + v.y) + (v.z + v.w);
  s += __shfl_xor(s, 32, 64);
  s += __shfl_xor(s, 16, 64);
  s += __shfl_xor(s, 8, 64);
  s += __shfl_xor(s, 4, 64);
  s += __shfl_xor(s, 2, 64);
  s += __shfl_xor(s, 1, 64);
  if (lane == 0) out[NB + i] = s * (1.0f / NP);
}

extern "C" void kernel_launch(void* const* d_in, const int* in_sizes, int n_in,
                              void* d_out, int out_size, void* d_ws, size_t ws_size,
                              hipStream_t stream) {
  (void)in_sizes; (void)n_in; (void)out_size; (void)ws_size;
  const float* input_data = (const float*)d_in[0];
  const float* y_prev     = (const float*)d_in[1];
  const float* Wv         = (const float*)d_in[2];
  const float* bv         = (const float*)d_in[3];
  const float* W_ih       = (const float*)d_in[4];
  const float* W_hh       = (const float*)d_in[5];
  const float* b_ih       = (const float*)d_in[6];
  const float* b_hh       = (const float*)d_in[7];
  const float* Wp         = (const float*)d_in[8];
  const float* bp         = (const float*)d_in[9];
  const float* Wf         = (const float*)d_in[10];
  const float* bf         = (const float*)d_in[11];
  float* out = (float*)d_out;
  float* gw  = (float*)d_ws;                           // [P][B] f32 = 512 KB

  FKeys fk;
  for (int t = 0; t < NT; ++t) {
    uint32_t x0 = 0u, x1 = (uint32_t)t;
    threefry2x32(0u, 1234u, x0, x1);
    fk.a[t] = x0; fk.b[t] = x1;
  }

  pf_main<<<dim3(NB), dim3(NTHR), 0, stream>>>(
      input_data, y_prev, Wv, bv, W_ih, W_hh, b_ih, b_hh, Wp, bp, Wf, bf,
      out, gw, fk);
  pf_weights<<<dim3(NB), dim3(64), 0, stream>>>(gw, out);
}

// Round 17
// 1342.275 us; speedup vs baseline: 1.1078x; 1.1078x over previous
//
#include <hip/hip_runtime.h>
#include <stdint.h>

#define NB 512   // batch
#define NT 32    // time steps
#define NIN 8    // input feats
#define NIN1 9   // + y_prev
#define NH 64    // hidden
#define NP 256   // particles
#define NTHR 512 // 8 waves: wave wq owns gate-rows r' in [32wq, 32wq+32)
#define HROW 68  // f16 row stride: 136 B = 34 dwords -> 2-way bank alias (free)

typedef __attribute__((ext_vector_type(8))) _Float16 f16x8;
typedef __attribute__((ext_vector_type(16))) float f32x16;

struct FKeys { uint32_t a[NT]; uint32_t b[NT]; };

// ---------------- Threefry-2x32-20 (exact JAX semantics) ----------------
__host__ __device__ __forceinline__ void tfr(uint32_t& x0, uint32_t& x1, int r) {
  x0 += x1; x1 = (x1 << r) | (x1 >> (32 - r)); x1 ^= x0;
}

__host__ __device__ __forceinline__ void threefry2x32(uint32_t k0, uint32_t k1,
                                                      uint32_t& x0, uint32_t& x1) {
  uint32_t k2 = k0 ^ k1 ^ 0x1BD11BDAu;
  x0 += k0; x1 += k1;
  tfr(x0,x1,13); tfr(x0,x1,15); tfr(x0,x1,26); tfr(x0,x1,6);
  x0 += k1; x1 += k2 + 1u;
  tfr(x0,x1,17); tfr(x0,x1,29); tfr(x0,x1,16); tfr(x0,x1,24);
  x0 += k2; x1 += k0 + 2u;
  tfr(x0,x1,13); tfr(x0,x1,15); tfr(x0,x1,26); tfr(x0,x1,6);
  x0 += k0; x1 += k1 + 3u;
  tfr(x0,x1,17); tfr(x0,x1,29); tfr(x0,x1,16); tfr(x0,x1,24);
  x0 += k1; x1 += k2 + 4u;
  tfr(x0,x1,13); tfr(x0,x1,15); tfr(x0,x1,26); tfr(x0,x1,6);
  x0 += k2; x1 += k0 + 5u;
}

// bits -> uniform -> sqrt(2)*erfinv  (XLA f32 path; __logf variant validated
// R11 at absmax 0.5).
__device__ __forceinline__ float normal_from_bits(uint32_t bits) {
  float f = __uint_as_float((bits >> 9) | 0x3f800000u) - 1.0f;
  const float lo = -0.99999994f;
  float u = fmaxf(lo, fmaf(f, 2.0f, lo));
  float w = -__logf(fmaf(-u, u, 1.0f));
  float p;
  if (w < 5.0f) {
    w -= 2.5f;
    p = 2.81022636e-08f;
    p = fmaf(p, w, 3.43273939e-07f);
    p = fmaf(p, w, -3.5233877e-06f);
    p = fmaf(p, w, -4.39150654e-06f);
    p = fmaf(p, w, 0.00021858087f);
    p = fmaf(p, w, -0.00125372503f);
    p = fmaf(p, w, -0.00417768164f);
    p = fmaf(p, w, 0.246640727f);
    p = fmaf(p, w, 1.50140941f);
  } else {
    w = sqrtf(w) - 3.0f;
    p = -0.000200214257f;
    p = fmaf(p, w, 0.000100950558f);
    p = fmaf(p, w, 0.00134934322f);
    p = fmaf(p, w, -0.00367342844f);
    p = fmaf(p, w, 0.00573950773f);
    p = fmaf(p, w, -0.0076224613f);
    p = fmaf(p, w, 0.00943887047f);
    p = fmaf(p, w, 1.00167406f);
    p = fmaf(p, w, 2.83297682f);
  }
  return 1.41421356f * (p * u);
}

__device__ __forceinline__ float frcp(float x) { return __builtin_amdgcn_rcpf(x); }
__device__ __forceinline__ float fsigmoid(float x) { return frcp(1.0f + __expf(-x)); }
__device__ __forceinline__ float ftanh(float x) { return 1.0f - 2.0f * frcp(1.0f + __expf(2.0f * x)); }

// f32 -> f16 bits (RNE)
__device__ __forceinline__ uint32_t pack_f16(float x) {
  union { _Float16 h; uint16_t u; } c;
  c.h = (_Float16)x;
  return (uint32_t)c.u;
}
// packed f16 pair access (compile-time hi flag)
__device__ __forceinline__ float unpk_f16(uint32_t w, int hi) {
  union { _Float16 h; uint16_t u; } c;
  c.u = hi ? (uint16_t)(w >> 16) : (uint16_t)(w & 0xffffu);
  return (float)c.h;
}

// 8B-aligned LDS f16x8 load (two ds_read_b64, 2-way alias at HROW=68)
__device__ __forceinline__ f16x8 ld8h(const _Float16* p) {
  union { f16x8 v; uint64_t q[2]; } u;
  u.q[0] = *(const uint64_t*)(p);
  u.q[1] = *(const uint64_t*)(p + 4);
  return u.v;
}

// ---------------- main kernel: one block (512 thr) per batch elem ----------------
// R15 structure (single-f16 h, h0 unsorted staging + phase-F permute copy), with
// the c state packed as f16 pairs (2 per u32): cA/cB 32 f32 regs -> 16 u32 regs.
// Target: arch VGPR <= 112 so arch + 16 acc-AGPR <= 128 -> 16 waves/CU.
__global__ __launch_bounds__(NTHR, 2)
void pf_main(const float* __restrict__ input_data, const float* __restrict__ y_prev,
             const float* __restrict__ Wv, const float* __restrict__ bv,
             const float* __restrict__ W_ih, const float* __restrict__ W_hh,
             const float* __restrict__ b_ih, const float* __restrict__ b_hh,
             const float* __restrict__ Wp, const float* __restrict__ bp,
             const float* __restrict__ Wf, const float* __restrict__ bf,
             float* __restrict__ out, float* __restrict__ gw,
             FKeys fk)
{
  __shared__ __align__(16) _Float16 h1_s[NP * HROW];  // 34.8 KB sorted h
  __shared__ __align__(16) _Float16 h0_s[NP * HROW];  // 34.8 KB unsorted new h
  __shared__ __align__(16) float xg_s[NP];
  __shared__ __align__(16) float proj_s[NP];
  __shared__ float lp_s[NP];
  __shared__ float wsum_s[NP];
  __shared__ int   rankP_s[2 * NP];
  __shared__ float hsum_s[NH];
  __shared__ float std_s[NH];
  __shared__ float xs_s[16];

  const int tid  = threadIdx.x;
  const int b    = blockIdx.x;
  const int lane = tid & 63;
  const int wq   = tid >> 6;          // wave 0..7: gate-row group
  const int ln31 = lane & 31;
  const int h5   = lane >> 5;

  for (int i = tid; i < NP * HROW; i += NTHR) h1_s[i] = (_Float16)0.0f;
  if (tid < NP) wsum_s[tid] = 0.0f;
  if (tid < NH) hsum_s[tid] = 0.0f;

  const float bf0 = bf[0];
  const float bp0 = bp[0];
  const uint32_t bsh = (uint32_t)b << 6;

  // W' A-fragments (single f16), loaded ONCE: r' = 32wq+ln31, orig row (r'&3)*64+(r'>>2)
  const int rp   = 32 * wq + ln31;
  const int orig = (rp & 3) * NH + (rp >> 2);
  f16x8 w1f[4];
  #pragma unroll
  for (int kt = 0; kt < 4; ++kt) {
    #pragma unroll
    for (int e = 0; e < 8; ++e)
      w1f[kt][e] = (_Float16)W_hh[orig * NH + kt * 16 + h5 * 8 + e];
  }

  float wf_r[4], wp_r[4];
  #pragma unroll
  for (int q = 0; q < 4; ++q) {
    const int kq = 8 * wq + 2 * q + h5;
    wf_r[q] = Wf[kq];
    wp_r[q] = Wp[kq];
  }

  // c state packed as f16 pairs (q-pairs): [mi][q>>1], never sorted
  uint32_t cAp[4][2], cBp[4][2];
  #pragma unroll
  for (int mi = 0; mi < 4; ++mi) {
    cAp[mi][0] = 0u; cAp[mi][1] = 0u;
    cBp[mi][0] = 0u; cBp[mi][1] = 0u;
  }

  auto finalize_init = [&]() {
    if (tid < NH) {
      float v = bv[tid];
      const float* wvr = Wv + tid * (NIN1 + NH);
      #pragma unroll
      for (int i = 0; i < NIN1; ++i) v = fmaf(xs_s[i], wvr[i], v);
      #pragma unroll
      for (int k = 0; k < NH; ++k)
        v = fmaf(hsum_s[k] * (1.0f / NP), wvr[NIN1 + k], v);
      std_s[tid] = fmaxf(v, 0.0f) + log1pf(expf(-fabsf(v)));   // softplus, libm exact
    }
    if (tid < NP) {
      const int orow = (tid & 3) * NH + (tid >> 2);
      float a = b_ih[orow] + b_hh[orow];
      const float* wr = W_ih + orow * NIN1;
      #pragma unroll
      for (int i = 0; i < NIN1; ++i) a = fmaf(xs_s[i], wr[i], a);
      xg_s[tid] = a;
      proj_s[tid] = bf0;
      float xp = bp0;
      #pragma unroll
      for (int i = 0; i < NIN1; ++i) xp = fmaf(xs_s[i], Wp[NH + i], xp);
      lp_s[tid] = xp;
    }
  };

  if (tid < NIN) xs_s[tid] = input_data[(b * NT + 0) * NIN + tid];
  if (tid == NIN) xs_s[NIN] = y_prev[b * NT + 0];
  __syncthreads();
  finalize_init();
  __syncthreads();

  for (int t = 0; t < NT; ++t) {
    // ================= phase A: MFMA + elementwise (+ xs_{t+1} prefetch) ========
    if (tid < 16 && t + 1 < NT) {
      if (tid < NIN) xs_s[tid] = input_data[(b * NT + t + 1) * NIN + tid];
      if (tid == NIN) xs_s[NIN] = y_prev[b * NT + t + 1];
    }

    float std_r[4];
    #pragma unroll
    for (int q = 0; q < 4; ++q) std_r[q] = std_s[8 * wq + 2 * q + h5];

    const uint32_t fk0 = fk.a[t], fk1 = fk.b[t];
    float hs[4] = {0.0f, 0.0f, 0.0f, 0.0f};

    #pragma unroll
    for (int mi = 0; mi < 4; ++mi) {
      const int pA = mi * 32 + ln31;

      // ---- tile A (rows pA) ----
      f32x16 acc;
      #pragma unroll
      for (int q = 0; q < 4; ++q) {
        const float4 v = *(const float4*)&xg_s[32 * wq + 8 * q + 4 * h5];
        acc[4 * q + 0] = v.x; acc[4 * q + 1] = v.y;
        acc[4 * q + 2] = v.z; acc[4 * q + 3] = v.w;
      }
      #pragma unroll
      for (int kt = 0; kt < 4; ++kt) {
        const f16x8 b1 = ld8h(&h1_s[pA * HROW + kt * 16 + h5 * 8]);
        acc = __builtin_amdgcn_mfma_f32_32x32x16_f16(w1f[kt], b1, acc, 0, 0, 0);
      }
      float hlA[4];
      #pragma unroll
      for (int q = 0; q < 4; ++q) {
        float si = fsigmoid(acc[4 * q + 0]);
        float sf = fsigmoid(acc[4 * q + 1]);
        float so = fsigmoid(acc[4 * q + 3]);
        float cold = unpk_f16(cAp[mi][q >> 1], q & 1);
        float cn = sf * cold + si * ftanh(acc[4 * q + 2]);
        const uint32_t pk = pack_f16(cn);
        if (q & 1) cAp[mi][q >> 1] = (cAp[mi][q >> 1] & 0x0000ffffu) | (pk << 16);
        else       cAp[mi][q >> 1] = (cAp[mi][q >> 1] & 0xffff0000u) | pk;
        hlA[q] = so * ftanh(cn);
      }
      // ---- tile B (rows pA+128) ----
      #pragma unroll
      for (int q = 0; q < 4; ++q) {
        const float4 v = *(const float4*)&xg_s[32 * wq + 8 * q + 4 * h5];
        acc[4 * q + 0] = v.x; acc[4 * q + 1] = v.y;
        acc[4 * q + 2] = v.z; acc[4 * q + 3] = v.w;
      }
      #pragma unroll
      for (int kt = 0; kt < 4; ++kt) {
        const f16x8 b1 = ld8h(&h1_s[(pA + 128) * HROW + kt * 16 + h5 * 8]);
        acc = __builtin_amdgcn_mfma_f32_32x32x16_f16(w1f[kt], b1, acc, 0, 0, 0);
      }
      float plA = 0.0f, lpA = 0.0f, plB = 0.0f, lpB = 0.0f;
      uint32_t sh[4];
      #pragma unroll
      for (int q = 0; q < 4; ++q) {
        const int kq = 8 * wq + 2 * q + h5;
        float si = fsigmoid(acc[4 * q + 0]);
        float sf = fsigmoid(acc[4 * q + 1]);
        float so = fsigmoid(acc[4 * q + 3]);
        float cold = unpk_f16(cBp[mi][q >> 1], q & 1);
        float cnB = sf * cold + si * ftanh(acc[4 * q + 2]);
        const uint32_t pkc = pack_f16(cnB);
        if (q & 1) cBp[mi][q >> 1] = (cBp[mi][q >> 1] & 0x0000ffffu) | (pkc << 16);
        else       cBp[mi][q >> 1] = (cBp[mi][q >> 1] & 0xffff0000u) | pkc;
        float hlB = so * ftanh(cnB);
        uint32_t x0 = ((uint32_t)pA << 15) | bsh | (uint32_t)kq;
        uint32_t x1 = x0 + (1u << 22);
        threefry2x32(fk0, fk1, x0, x1);
        float hA = fmaf(normal_from_bits(x0), std_r[q], hlA[q]);
        float hB = fmaf(normal_from_bits(x1), std_r[q], hlB);
        hs[q] += hA + hB;
        plA = fmaf(hA, wf_r[q], plA); lpA = fmaf(hA, wp_r[q], lpA);
        plB = fmaf(hB, wf_r[q], plB); lpB = fmaf(hB, wp_r[q], lpB);
        // cross-lane exchange: assemble this thread's write row-half (f16 pair)
        const uint32_t pkA = pack_f16(hA);
        const uint32_t pkB = pack_f16(hB);
        const uint32_t send = h5 ? pkA : pkB;
        const uint32_t got  = (uint32_t)__shfl_xor((int)send, 32, 64);
        const uint32_t ev = h5 ? got : pkA;   // k = 8wq+2q   (even)
        const uint32_t od = h5 ? pkB : got;   // k = 8wq+2q+1 (odd)
        sh[q] = (ev & 0xffffu) | (od << 16);
      }
      // immediate unsorted store -> h0_s (frees the staging registers)
      {
        const int row = pA + (h5 ? 128 : 0);
        _Float16* d = &h0_s[row * HROW + 8 * wq];
        *(uint64_t*)(d)     = (uint64_t)sh[0] | ((uint64_t)sh[1] << 32);
        *(uint64_t*)(d + 4) = (uint64_t)sh[2] | ((uint64_t)sh[3] << 32);
      }
      plA += __shfl_xor(plA, 32, 64); lpA += __shfl_xor(lpA, 32, 64);
      plB += __shfl_xor(plB, 32, 64); lpB += __shfl_xor(lpB, 32, 64);
      if (lane < 32) {
        atomicAdd(&proj_s[pA], plA);
        atomicAdd(&lp_s[pA], lpA);
        atomicAdd(&proj_s[pA + 128], plB);
        atomicAdd(&lp_s[pA + 128], lpB);
      }
    }
    // hsum: butterfly over 32-lane group; k = 8wq+2q+h5
    #pragma unroll
    for (int q = 0; q < 4; ++q) {
      float s = hs[q];
      s += __shfl_xor(s, 1, 64); s += __shfl_xor(s, 2, 64); s += __shfl_xor(s, 4, 64);
      s += __shfl_xor(s, 8, 64); s += __shfl_xor(s, 16, 64);
      if (ln31 == q) hsum_s[8 * wq + 2 * q + h5] = s;
    }
    __syncthreads();   // b1: h1 reads + h0 writes + proj/lp atomics + xs_next done

    // ================= phase R: split stable-rank (512 half-jobs) =================
    {
      const int ph = tid & (NP - 1);
      const int hh = tid >> 8;
      const float pv = proj_s[ph];
      int rk = 0;
      const float4* c4 = (const float4*)proj_s;
      #pragma unroll 8
      for (int q4 = 32 * hh; q4 < 32 * hh + 32; ++q4) {
        float4 v = c4[q4];
        int qb = q4 * 4;
        rk += (v.x < pv || (v.x == pv && qb + 0 < ph)) ? 1 : 0;
        rk += (v.y < pv || (v.y == pv && qb + 1 < ph)) ? 1 : 0;
        rk += (v.z < pv || (v.z == pv && qb + 2 < ph)) ? 1 : 0;
        rk += (v.w < pv || (v.w == pv && qb + 3 < ph)) ? 1 : 0;
      }
      rankP_s[hh * NP + ph] = rk;
    }
    __syncthreads();   // b2: rank partials ready

    // ================= phase F: copy h0[p] -> h1[rank[p]] + wsum + next init ====
    {
      const int ph = tid & (NP - 1);
      const int hh = tid >> 8;
      const int rank = rankP_s[ph] + rankP_s[NP + ph];
      const uint64_t* s = (const uint64_t*)&h0_s[ph * HROW + 32 * hh];
      const uint64_t v0 = s[0], v1 = s[1], v2 = s[2], v3 = s[3];
      uint64_t* d = (uint64_t*)&h1_s[rank * HROW + 32 * hh];
      d[0] = v0; d[1] = v1; d[2] = v2; d[3] = v3;
      if (hh == 0) wsum_s[rank] += __expf(lp_s[ph]);   // permutation -> race-free
    }
    finalize_init();
    __syncthreads();   // b3 (loop end): h writes + next-step init visible
  }

  // ---- epilogue: y_pred[b] = mean_p(h_fin) @ Wf + bf ----
  if (tid < NH) {
    float hm = hsum_s[tid] * (1.0f / NP);
    float contrib = hm * Wf[tid];
    contrib += __shfl_xor(contrib, 32, 64);
    contrib += __shfl_xor(contrib, 16, 64);
    contrib += __shfl_xor(contrib, 8, 64);
    contrib += __shfl_xor(contrib, 4, 64);
    contrib += __shfl_xor(contrib, 2, 64);
    contrib += __shfl_xor(contrib, 1, 64);
    if (tid == 0) out[b] = contrib + bf0;
  }
  if (tid < NP) gw[(size_t)tid * NB + b] = wsum_s[tid];
}

// weights[i] = (1/256) * sum_{j<256} gw[(i>>1)*512 + (i&1)*256 + j]
__global__ __launch_bounds__(64, 1)
void pf_weights(const float* __restrict__ gw, float* __restrict__ out) {
  int i = blockIdx.x;
  int lane = threadIdx.x;
  const float* src = gw + ((size_t)(i >> 1)) * NB + (size_t)(i & 1) * NP;
  float4 v = ((const float4*)src)[lane];
  float s = (v.x + v.y) + (v.z + v.w);
  s += __shfl_xor(s, 32, 64);
  s += __shfl_xor(s, 16, 64);
  s += __shfl_xor(s, 8, 64);
  s += __shfl_xor(s, 4, 64);
  s += __shfl_xor(s, 2, 64);
  s += __shfl_xor(s, 1, 64);
  if (lane == 0) out[NB + i] = s * (1.0f / NP);
}

extern "C" void kernel_launch(void* const* d_in, const int* in_sizes, int n_in,
                              void* d_out, int out_size, void* d_ws, size_t ws_size,
                              hipStream_t stream) {
  (void)in_sizes; (void)n_in; (void)out_size; (void)ws_size;
  const float* input_data = (const float*)d_in[0];
  const float* y_prev     = (const float*)d_in[1];
  const float* Wv         = (const float*)d_in[2];
  const float* bv         = (const float*)d_in[3];
  const float* W_ih       = (const float*)d_in[4];
  const float* W_hh       = (const float*)d_in[5];
  const float* b_ih       = (const float*)d_in[6];
  const float* b_hh       = (const float*)d_in[7];
  const float* Wp         = (const float*)d_in[8];
  const float* bp         = (const float*)d_in[9];
  const float* Wf         = (const float*)d_in[10];
  const float* bf         = (const float*)d_in[11];
  float* out = (float*)d_out;
  float* gw  = (float*)d_ws;                           // [P][B] f32 = 512 KB

  FKeys fk;
  for (int t = 0; t < NT; ++t) {
    uint32_t x0 = 0u, x1 = (uint32_t)t;
    threefry2x32(0u, 1234u, x0, x1);
    fk.a[t] = x0; fk.b[t] = x1;
  }

  pf_main<<<dim3(NB), dim3(NTHR), 0, stream>>>(
      input_data, y_prev, Wv, bv, W_ih, W_hh, b_ih, b_hh, Wp, bp, Wf, bf,
      out, gw, fk);
  pf_weights<<<dim3(NB), dim3(64), 0, stream>>>(gw, out);
}